// Round 1
// baseline (190.651 us; speedup 1.0000x reference)
//
#include <hip/hip_runtime.h>
#include <math.h>

#define NK 256
#define NT 128
#define NC 32
#define ND 10
#define NSPK 1000000
#define NPAIR 55            // number of i<=j pairs for D=10
#define CSTRIDE 68          // 55 quad + 10 lin + 1 const, padded
#define LOG2PI 1.8378770664093453f

// ws layout:
//   [0, 8)        double accumulator
//   [256, ~9K)    float coefs[NC][CSTRIDE]
//   [16384, +4MB) float pisT[NK*NT][NC]   (log_pis transposed: contiguous in c)

// ---------------- Prep A: per-component quadratic-form coefficients ----------
__global__ void prep_coef_kernel(const float* __restrict__ means,
                                 const float* __restrict__ covs,
                                 float* __restrict__ coefs) {
  int c = threadIdx.x;
  if (c >= NC) return;

  float A[ND][ND];
  #pragma unroll
  for (int i = 0; i < ND; ++i)
    #pragma unroll
    for (int j = 0; j < ND; ++j)
      A[i][j] = covs[c * ND * ND + i * ND + j];

  // Cholesky A = L L^T
  float L[ND][ND];
  #pragma unroll
  for (int i = 0; i < ND; ++i)
    #pragma unroll
    for (int j = 0; j < ND; ++j) L[i][j] = 0.f;

  float logdet = 0.f;
  #pragma unroll
  for (int j = 0; j < ND; ++j) {
    float sum = A[j][j];
    #pragma unroll
    for (int k = 0; k < ND; ++k) if (k < j) sum -= L[j][k] * L[j][k];
    float ljj = sqrtf(sum);
    L[j][j] = ljj;
    logdet += 2.f * __logf(ljj);
    float inv = 1.f / ljj;
    #pragma unroll
    for (int i = 0; i < ND; ++i) {
      if (i > j) {
        float s2 = A[i][j];
        #pragma unroll
        for (int k = 0; k < ND; ++k) if (k < j) s2 -= L[i][k] * L[j][k];
        L[i][j] = s2 * inv;
      }
    }
  }

  // invert lower-triangular L -> Li
  float Li[ND][ND];
  #pragma unroll
  for (int i = 0; i < ND; ++i)
    #pragma unroll
    for (int j = 0; j < ND; ++j) Li[i][j] = 0.f;
  #pragma unroll
  for (int j = 0; j < ND; ++j) {
    Li[j][j] = 1.f / L[j][j];
    #pragma unroll
    for (int i = 0; i < ND; ++i) {
      if (i > j) {
        float s2 = 0.f;
        #pragma unroll
        for (int k = 0; k < ND; ++k) if (k >= j && k < i) s2 += L[i][k] * Li[k][j];
        Li[i][j] = -s2 / L[i][i];
      }
    }
  }

  // P = Li^T Li (precision matrix)
  float P[ND][ND];
  #pragma unroll
  for (int i = 0; i < ND; ++i)
    #pragma unroll
    for (int j = 0; j < ND; ++j) {
      if (j >= i) {
        float s2 = 0.f;
        #pragma unroll
        for (int k = 0; k < ND; ++k) if (k >= j) s2 += Li[k][i] * Li[k][j];
        P[i][j] = s2;
      }
    }
  #pragma unroll
  for (int i = 0; i < ND; ++i)
    #pragma unroll
    for (int j = 0; j < ND; ++j) if (j < i) P[i][j] = P[j][i];

  float mu[ND], q[ND];
  #pragma unroll
  for (int i = 0; i < ND; ++i) mu[i] = means[c * ND + i];
  float muPmu = 0.f;
  #pragma unroll
  for (int i = 0; i < ND; ++i) {
    float acc = 0.f;
    #pragma unroll
    for (int j = 0; j < ND; ++j) acc += P[i][j] * mu[j];
    q[i] = acc;
    muPmu += mu[i] * acc;
  }
  float cst = -0.5f * ((float)ND * LOG2PI + logdet + muPmu);

  // pack: ll_c(s) = cst + sum_i q_i s_i + sum_{i<=j} w_ij * (s_i s_j)
  float* out = coefs + c * CSTRIDE;
  int idx = 0;
  #pragma unroll
  for (int i = 0; i < ND; ++i)
    #pragma unroll
    for (int j = 0; j < ND; ++j)
      if (j >= i) out[idx++] = (i == j) ? -0.5f * P[i][i] : -P[i][j];
  #pragma unroll
  for (int i = 0; i < ND; ++i) out[NPAIR + i] = q[i];
  out[NPAIR + ND] = cst;   // index 65
  out[66] = 0.f;
  out[67] = 0.f;
}

// ---------------- Prep B: log_pis table, transposed [k][t][c] ----------------
__global__ void prep_pis_kernel(const float* __restrict__ y,
                                const float* __restrict__ b_mu,
                                const float* __restrict__ beta_mu,
                                float* __restrict__ pisT) {
  int id = blockIdx.x * blockDim.x + threadIdx.x;   // id = k*NT + t
  int t = id & (NT - 1);
  float yv = y[id];
  float v[NC];
  float m = -1e30f;
  #pragma unroll
  for (int c = 0; c < NC; ++c) {
    v[c] = fmaf(beta_mu[c * NT + t], yv, b_mu[c]);
    m = fmaxf(m, v[c]);
  }
  float ssum = 0.f;
  #pragma unroll
  for (int c = 0; c < NC; ++c) ssum += __expf(v[c] - m);
  float lz = m + __logf(ssum);
  float* out = pisT + id * NC;
  #pragma unroll
  for (int c = 0; c < NC; ++c) out[c] = v[c] - lz;
}

// ---------------- Prep C: prior - q scalar terms -----------------------------
__global__ void prep_scalars_kernel(const float* __restrict__ b_mu,
                                    const float* __restrict__ b_ls,
                                    const float* __restrict__ beta_mu,
                                    const float* __restrict__ beta_ls,
                                    double* __restrict__ acc) {
  int tid = threadIdx.x;
  float local = 0.f;
  for (int i = tid; i < NC; i += 256)
    local += fmaf(-0.5f * b_mu[i], b_mu[i], b_ls[i]);
  for (int i = tid; i < NC * NT; i += 256)
    local += fmaf(-0.5f * beta_mu[i], beta_mu[i], beta_ls[i]);
  #pragma unroll
  for (int off = 32; off > 0; off >>= 1) local += __shfl_down(local, off);
  __shared__ float red[4];
  if ((tid & 63) == 0) red[tid >> 6] = local;
  __syncthreads();
  if (tid == 0) atomicAdd(acc, (double)(red[0] + red[1] + red[2] + red[3]));
}

// ---------------- Main: per-spike logsumexp ----------------------------------
__global__ __launch_bounds__(256)
void spike_kernel(const float* __restrict__ s,
                  const int* __restrict__ ks,
                  const int* __restrict__ ts,
                  const float* __restrict__ coefs,
                  const float* __restrict__ pisT,
                  double* __restrict__ acc) {
  int n = blockIdx.x * 256 + threadIdx.x;
  float lse = 0.f;
  if (n < NSPK) {
    // load s row (40B, 8B-aligned) as 5x float2
    const float2* srow = (const float2*)(s + n * ND);
    float sv[ND];
    #pragma unroll
    for (int i = 0; i < 5; ++i) {
      float2 v2 = srow[i];
      sv[2 * i] = v2.x;
      sv[2 * i + 1] = v2.y;
    }
    int k = ks[n], t = ts[n];
    const float4* lp4 = (const float4*)(pisT + (k * NT + t) * NC);

    // 55 cross products, reused across all 32 components
    float feat[NPAIR];
    {
      int idx = 0;
      #pragma unroll
      for (int i = 0; i < ND; ++i)
        #pragma unroll
        for (int j = 0; j < ND; ++j)
          if (j >= i) feat[idx++] = sv[i] * sv[j];
    }

    float m = -1e30f, ssum = 0.f;
    for (int g = 0; g < NC / 4; ++g) {
      float4 lpv = lp4[g];
      float lparr[4] = {lpv.x, lpv.y, lpv.z, lpv.w};
      #pragma unroll
      for (int cc = 0; cc < 4; ++cc) {
        const float* __restrict__ w = coefs + (g * 4 + cc) * CSTRIDE;
        float a = w[NPAIR + ND];                       // const term
        #pragma unroll
        for (int i = 0; i < ND; ++i) a = fmaf(sv[i], w[NPAIR + i], a);
        #pragma unroll
        for (int p = 0; p < NPAIR; ++p) a = fmaf(feat[p], w[p], a);
        float v = a + lparr[cc];
        // online logsumexp, single exp per component
        float d = v - m;
        float e = __expf(-fabsf(d));
        bool gt = d > 0.f;
        ssum = gt ? fmaf(ssum, e, 1.f) : (ssum + e);
        m = gt ? v : m;
      }
    }
    lse = m + __logf(ssum);
  }

  // block reduction -> one fp64 atomic per block
  #pragma unroll
  for (int off = 32; off > 0; off >>= 1) lse += __shfl_down(lse, off);
  __shared__ float red[4];
  if ((threadIdx.x & 63) == 0) red[threadIdx.x >> 6] = lse;
  __syncthreads();
  if (threadIdx.x == 0)
    atomicAdd(acc, (double)(red[0] + red[1] + red[2] + red[3]));
}

// ---------------- Finalize ---------------------------------------------------
__global__ void finalize_kernel(const double* __restrict__ acc,
                                float* __restrict__ out) {
  if (threadIdx.x == 0) out[0] = (float)acc[0];
}

extern "C" void kernel_launch(void* const* d_in, const int* in_sizes, int n_in,
                              void* d_out, int out_size, void* d_ws, size_t ws_size,
                              hipStream_t stream) {
  const float* s       = (const float*)d_in[0];
  const float* y       = (const float*)d_in[1];
  const int*   ks      = (const int*)d_in[2];
  const int*   ts      = (const int*)d_in[3];
  const float* means   = (const float*)d_in[4];
  const float* covs    = (const float*)d_in[5];
  const float* b_mu    = (const float*)d_in[6];
  const float* b_ls    = (const float*)d_in[7];
  const float* beta_mu = (const float*)d_in[8];
  const float* beta_ls = (const float*)d_in[9];
  float* out = (float*)d_out;

  char* ws = (char*)d_ws;
  double* acc  = (double*)ws;
  float* coefs = (float*)(ws + 256);
  float* pisT  = (float*)(ws + 16384);

  hipMemsetAsync(ws, 0, 64, stream);
  prep_coef_kernel<<<1, 64, 0, stream>>>(means, covs, coefs);
  prep_pis_kernel<<<(NK * NT) / 256, 256, 0, stream>>>(y, b_mu, beta_mu, pisT);
  prep_scalars_kernel<<<1, 256, 0, stream>>>(b_mu, b_ls, beta_mu, beta_ls, acc);
  spike_kernel<<<(NSPK + 255) / 256, 256, 0, stream>>>(s, ks, ts, coefs, pisT, acc);
  finalize_kernel<<<1, 64, 0, stream>>>(acc, out);
}